// Round 6
// baseline (223.045 us; speedup 1.0000x reference)
//
#include <hip/hip_runtime.h>
#include <math.h>

typedef __attribute__((ext_vector_type(8))) short bf16x8;
typedef __attribute__((ext_vector_type(4))) float f32x4;

__device__ __forceinline__ unsigned short f2bf(float f) {
  unsigned u = __float_as_uint(f);
  u += 0x7fffu + ((u >> 16) & 1u);  // round-to-nearest-even
  return (unsigned short)(u >> 16);
}
__device__ __forceinline__ float bflo(unsigned u) { return __uint_as_float(u << 16); }
__device__ __forceinline__ float bfhi(unsigned u) { return __uint_as_float(u & 0xffff0000u); }

// ================= CSR via two-level bucket binning =================
// Buckets of 256 nodes (NB = ceil(N/256)). packed edge = (d_local<<16)|src.
// Requires N <= 65536 — N = 50000 here.

constexpr int CB = 64;  // bucket_count blocks

// Blocks 0..CB-1: per-block partial bucket histograms.
// Blocks CB..CB+12: pack W1/W2/W3 into MFMA B-fragment order (independent work).
// Fragment (s,ct): lane l holds B[k=s*32+(l>>4)*8+j][col=ct*16+(l&15)], j=0..7.
__global__ __launch_bounds__(256) void count_pack(const int* __restrict__ dst,
                                                  int* __restrict__ partial, int E,
                                                  const float* __restrict__ W1,
                                                  const float* __restrict__ W2,
                                                  const float* __restrict__ W3,
                                                  unsigned short* __restrict__ Wp1,
                                                  unsigned short* __restrict__ Wp2,
                                                  unsigned short* __restrict__ Wp3) {
  int tid = threadIdx.x;
  if (blockIdx.x < CB) {
    __shared__ int bkt[256];
    bkt[tid] = 0;
    __syncthreads();
    int E4 = E >> 2;
    const int4* d4 = (const int4*)dst;
    for (int i = blockIdx.x * 256 + tid; i < E4; i += CB * 256) {
      int4 d = d4[i];
      atomicAdd(&bkt[d.x >> 8], 1);
      atomicAdd(&bkt[d.y >> 8], 1);
      atomicAdd(&bkt[d.z >> 8], 1);
      atomicAdd(&bkt[d.w >> 8], 1);
    }
    if (blockIdx.x == 0 && tid < (E & 3)) atomicAdd(&bkt[dst[E4 * 4 + tid] >> 8], 1);
    __syncthreads();
    partial[blockIdx.x * 256 + tid] = bkt[tid];
    return;
  }
  int gid = (blockIdx.x - CB) * 256 + tid;
  const float* W;
  unsigned short* Wp;
  int t, NCTT, M, MV;
  if (gid < 1536) {            // W1: 4 ksteps * 6 coltiles * 64 lanes
    W = W1; Wp = Wp1; t = gid; NCTT = 6; M = 96; MV = 96;
  } else if (gid < 2688) {     // W2: 3 * 6 * 64
    W = W2; Wp = Wp2; t = gid - 1536; NCTT = 6; M = 96; MV = 96;
  } else if (gid < 3264) {     // W3: 3 * 3 * 64 (cols >= 40 zero-padded)
    W = W3; Wp = Wp3; t = gid - 2688; NCTT = 3; M = 40; MV = 40;
  } else {
    return;
  }
  int lane = t & 63;
  int frag = t >> 6;
  int s = frag / NCTT;
  int ct = frag - s * NCTT;
  int colv = ct * 16 + (lane & 15);
  int k0 = s * 32 + (lane >> 4) * 8;
  union { unsigned short s[8]; uint4 u; } pk;
#pragma unroll
  for (int j = 0; j < 8; ++j) {
    float v = (colv < MV) ? W[(k0 + j) * M + colv] : 0.f;
    pk.s[j] = f2bf(v);
  }
  ((uint4*)Wp)[t] = pk.u;
}

// One block: reduce partials + exclusive scan over NB buckets.
__global__ __launch_bounds__(256) void scan_kernel(const int* __restrict__ partial,
                                                   int* __restrict__ gstart,
                                                   int* __restrict__ gcur,
                                                   int* __restrict__ row_ptr,
                                                   int NB, int N, int E) {
  int tid = threadIdx.x;
  int s = 0;
#pragma unroll 8
  for (int i = 0; i < CB; ++i) s += partial[i * 256 + tid];  // buckets >= NB sum to 0
  __shared__ int sm[256];
  sm[tid] = s;
  __syncthreads();
  for (int off = 1; off < 256; off <<= 1) {
    int u = (tid >= off) ? sm[tid - off] : 0;
    __syncthreads();
    sm[tid] += u;
    __syncthreads();
  }
  int excl = sm[tid] - s;
  if (tid < NB) { gstart[tid] = excl; gcur[tid] = excl; }
  if (tid == NB - 1) gstart[NB] = sm[tid];
  if (tid == 0) row_ptr[N] = E;
}

// Blocks 0..NBIN-1: bin edges into bucket-contiguous packed array.
// Blocks NBIN..: gemm1 (t1 = bf16(x) @ W1), independent of the binning.
__global__ __launch_bounds__(256) void bin_gemm1(const int* __restrict__ src,
                                                 const int* __restrict__ dst,
                                                 int* __restrict__ gcur,
                                                 int* __restrict__ packed, int E, int NB,
                                                 int NBIN, const float* __restrict__ x,
                                                 const unsigned short* __restrict__ Wp1,
                                                 unsigned short* __restrict__ Tb, int N) {
  int tid = threadIdx.x;
  if (blockIdx.x < NBIN) {
    __shared__ int lcnt[256];
    __shared__ int gbase[256];
    lcnt[tid] = 0;
    __syncthreads();
    int idx = blockIdx.x * 256 + tid;  // int4 index
    int E4 = E >> 2;
    int sv[4], dv[4], lv[4];
    int cnt = 0;
    if (idx < E4) {
      int4 s4 = ((const int4*)src)[idx];
      int4 d4 = ((const int4*)dst)[idx];
      sv[0] = s4.x; sv[1] = s4.y; sv[2] = s4.z; sv[3] = s4.w;
      dv[0] = d4.x; dv[1] = d4.y; dv[2] = d4.z; dv[3] = d4.w;
      cnt = 4;
    } else if (idx == E4 && (E & 3)) {
      int tl = E & 3;
      for (int i = 0; i < tl; ++i) { sv[i] = src[E4 * 4 + i]; dv[i] = dst[E4 * 4 + i]; }
      cnt = tl;
    }
    for (int i = 0; i < cnt; ++i) lv[i] = atomicAdd(&lcnt[dv[i] >> 8], 1);
    __syncthreads();
    if (tid < NB) gbase[tid] = atomicAdd(&gcur[tid], lcnt[tid]);
    __syncthreads();
    for (int i = 0; i < cnt; ++i) {
      int b = dv[i] >> 8;
      packed[gbase[b] + lv[i]] = ((dv[i] & 255) << 16) | (sv[i] & 0xffff);
    }
    return;
  }
  // ---- gemm1: 16 rows x 96 cols per wave, KSTEPS=4, single pass over x ----
  int bx = blockIdx.x - NBIN;
  int wid = tid >> 6;
  int lane = tid & 63;
  int rt = bx * 4 + wid;
  if (rt * 16 >= N) return;
  int quad = lane >> 4;
  int lm = lane & 15;
  union BU { uint4 u; bf16x8 v; };
  bf16x8 bfrag[4][6];
  const uint4* wp4 = (const uint4*)Wp1;
#pragma unroll
  for (int s = 0; s < 4; ++s)
#pragma unroll
    for (int c = 0; c < 6; ++c) {
      BU bu;
      bu.u = wp4[(s * 6 + c) * 64 + lane];
      bfrag[s][c] = bu.v;
    }
  f32x4 acc[6];
#pragma unroll
  for (int c = 0; c < 6; ++c) acc[c] = (f32x4){0.f, 0.f, 0.f, 0.f};
  int row = rt * 16 + lm;
  if (row >= N) row = N - 1;
#pragma unroll
  for (int s = 0; s < 4; ++s) {
    int k0 = s * 32 + quad * 8;
    const float* Af = x + (size_t)row * 128 + k0;
    float4 x0 = *(const float4*)(Af);
    float4 x1 = *(const float4*)(Af + 4);
    union { unsigned short s[8]; bf16x8 v; } au;
    au.s[0] = f2bf(x0.x); au.s[1] = f2bf(x0.y); au.s[2] = f2bf(x0.z); au.s[3] = f2bf(x0.w);
    au.s[4] = f2bf(x1.x); au.s[5] = f2bf(x1.y); au.s[6] = f2bf(x1.z); au.s[7] = f2bf(x1.w);
#pragma unroll
    for (int c = 0; c < 6; ++c)
      acc[c] = __builtin_amdgcn_mfma_f32_16x16x32_bf16(au.v, bfrag[s][c], acc[c], 0, 0, 0);
  }
#pragma unroll
  for (int c = 0; c < 6; ++c) {
    int colv = c * 16 + lm;
#pragma unroll
    for (int r = 0; r < 4; ++r) {
      int orow = rt * 16 + quad * 4 + r;
      if (orow < N) Tb[(size_t)orow * 96 + colv] = f2bf(acc[c][r]);
    }
  }
}

// One block per 256-node bucket: local count -> local scan -> row_ptr + col.
__global__ __launch_bounds__(256) void build_local_csr(const int* __restrict__ packed,
                                                       const int* __restrict__ gstart,
                                                       int* __restrict__ row_ptr,
                                                       int* __restrict__ col, int N) {
  __shared__ int cnt[256];
  __shared__ int sm[256];
  int b = blockIdx.x, tid = threadIdx.x;
  int gs = gstart[b], ge = gstart[b + 1];
  int me = ge - gs;
  int node0 = b << 8;
  int RL = N - node0;
  if (RL > 256) RL = 256;
  cnt[tid] = 0;
  __syncthreads();
  for (int i = tid; i < me; i += 256) atomicAdd(&cnt[packed[gs + i] >> 16], 1);
  __syncthreads();
  int v = cnt[tid];
  sm[tid] = v;
  __syncthreads();
  for (int off = 1; off < 256; off <<= 1) {
    int u = (tid >= off) ? sm[tid - off] : 0;
    __syncthreads();
    sm[tid] += u;
    __syncthreads();
  }
  int excl = gs + sm[tid] - v;
  __syncthreads();
  cnt[tid] = excl;  // repurpose as cursor
  if (tid < RL) row_ptr[node0 + tid] = excl;
  __syncthreads();
  for (int i = tid; i < me; i += 256) {
    int pk = packed[gs + i];
    int p = atomicAdd(&cnt[pk >> 16], 1);
    col[p] = pk & 0xffff;
  }
}

// ================= Fused aggregation + GEMM =================
// Block owns 64 nodes. Phase A: h = relu(agg(tin)+bias) for those nodes -> LDS
// (bf16, row stride 104 for 16B alignment + uniform bank coverage). Phase B:
// 4 waves x 16-row MFMA tiles compute h @ W (NCT col tiles), write bf16.

template <int NCT, int MOUT, int MVALID>
__global__ __launch_bounds__(256) void fused_agg_gemm(const unsigned short* __restrict__ tin,
                                                      const int* __restrict__ row_ptr,
                                                      const int* __restrict__ col,
                                                      const float* __restrict__ bias,
                                                      const unsigned short* __restrict__ Wp,
                                                      unsigned short* __restrict__ outp, int N) {
  constexpr int LST = 104;  // bf16 units per LDS row
  __shared__ unsigned short sH[64 * LST];
  int tid = threadIdx.x;
  int node0 = blockIdx.x * 64;

  // ---- Phase A: aggregate 64 nodes x 12 chunks of 8 bf16 ----
#pragma unroll
  for (int it = 0; it < 3; ++it) {
    int u = tid + it * 256;
    int nl = u / 12;
    int c = u - nl * 12;
    int node = node0 + nl;
    if (node < N) {
      int beg = row_ptr[node];
      int end = row_ptr[node + 1];
      const unsigned short* tc = tin + 8 * c;
      float a0 = 0.f, a1 = 0.f, a2 = 0.f, a3 = 0.f, a4 = 0.f, a5 = 0.f, a6 = 0.f, a7 = 0.f;
      int e = beg;
      for (; e + 1 < end; e += 2) {
        int s0 = col[e], s1 = col[e + 1];
        uint4 u4 = *(const uint4*)(tc + (size_t)s0 * 96);
        uint4 w4 = *(const uint4*)(tc + (size_t)s1 * 96);
        a0 += bflo(u4.x); a1 += bfhi(u4.x);
        a2 += bflo(u4.y); a3 += bfhi(u4.y);
        a4 += bflo(u4.z); a5 += bfhi(u4.z);
        a6 += bflo(u4.w); a7 += bfhi(u4.w);
        a0 += bflo(w4.x); a1 += bfhi(w4.x);
        a2 += bflo(w4.y); a3 += bfhi(w4.y);
        a4 += bflo(w4.z); a5 += bfhi(w4.z);
        a6 += bflo(w4.w); a7 += bfhi(w4.w);
      }
      if (e < end) {
        int s0 = col[e];
        uint4 u4 = *(const uint4*)(tc + (size_t)s0 * 96);
        a0 += bflo(u4.x); a1 += bfhi(u4.x);
        a2 += bflo(u4.y); a3 += bfhi(u4.y);
        a4 += bflo(u4.z); a5 += bfhi(u4.z);
        a6 += bflo(u4.w); a7 += bfhi(u4.w);
      }
      const float* b = bias + 8 * c;
      union { unsigned short s[8]; uint4 u; } pk;
      pk.s[0] = f2bf(fmaxf(a0 + b[0], 0.f));
      pk.s[1] = f2bf(fmaxf(a1 + b[1], 0.f));
      pk.s[2] = f2bf(fmaxf(a2 + b[2], 0.f));
      pk.s[3] = f2bf(fmaxf(a3 + b[3], 0.f));
      pk.s[4] = f2bf(fmaxf(a4 + b[4], 0.f));
      pk.s[5] = f2bf(fmaxf(a5 + b[5], 0.f));
      pk.s[6] = f2bf(fmaxf(a6 + b[6], 0.f));
      pk.s[7] = f2bf(fmaxf(a7 + b[7], 0.f));
      *(uint4*)&sH[nl * LST + c * 8] = pk.u;
    }
  }
  __syncthreads();

  // ---- Phase B: MFMA tile per wave ----
  int wid = tid >> 6;
  int lane = tid & 63;
  int rt16 = wid * 16;  // local row base
  if (node0 + rt16 >= N) return;
  int quad = lane >> 4;
  int lm = lane & 15;
  union BU { uint4 u; bf16x8 v; };
  bf16x8 bfrag[3][NCT];
  const uint4* wp4 = (const uint4*)Wp;
#pragma unroll
  for (int s = 0; s < 3; ++s)
#pragma unroll
    for (int c = 0; c < NCT; ++c) {
      BU bu;
      bu.u = wp4[(s * NCT + c) * 64 + lane];
      bfrag[s][c] = bu.v;
    }
  f32x4 acc[NCT];
#pragma unroll
  for (int c = 0; c < NCT; ++c) acc[c] = (f32x4){0.f, 0.f, 0.f, 0.f};
#pragma unroll
  for (int s = 0; s < 3; ++s) {
    BU au;
    au.u = *(const uint4*)&sH[(rt16 + lm) * LST + s * 32 + quad * 8];
#pragma unroll
    for (int c = 0; c < NCT; ++c)
      acc[c] = __builtin_amdgcn_mfma_f32_16x16x32_bf16(au.v, bfrag[s][c], acc[c], 0, 0, 0);
  }
#pragma unroll
  for (int c = 0; c < NCT; ++c) {
    int colv = c * 16 + lm;
    if (colv >= MVALID) continue;
#pragma unroll
    for (int r = 0; r < 4; ++r) {
      int orow = node0 + rt16 + quad * 4 + r;
      if (orow < N) outp[(size_t)orow * MOUT + colv] = f2bf(acc[c][r]);
    }
  }
}

// Layer-3 aggregation (bf16 in) + bias + log_softmax over 40 classes.
// 16-lane group per node; lanes 0..9 each hold 4 classes.
__global__ void agg_lsm_bf16(const unsigned short* __restrict__ t,
                             const int* __restrict__ row_ptr, const int* __restrict__ col,
                             const float* __restrict__ bias, float* __restrict__ out, int N) {
  int tid = threadIdx.x;
  int node = blockIdx.x * 16 + (tid >> 4);
  int c = tid & 15;  // 0..9 active
  bool act = (c < 10) && (node < N);
  int ceff = (c < 10) ? c : 0;
  int beg = 0, end = 0;
  if (node < N) {
    beg = row_ptr[node];
    end = row_ptr[node + 1];
  }
  const unsigned short* tc = t + 4 * ceff;
  float v0 = 0.f, v1 = 0.f, v2 = 0.f, v3 = 0.f;
  if (act) {
    int e = beg;
    for (; e + 1 < end; e += 2) {
      int s0 = col[e], s1 = col[e + 1];
      uint2 u = *(const uint2*)(tc + (size_t)s0 * 40);
      uint2 w = *(const uint2*)(tc + (size_t)s1 * 40);
      v0 += bflo(u.x); v1 += bfhi(u.x);
      v2 += bflo(u.y); v3 += bfhi(u.y);
      v0 += bflo(w.x); v1 += bfhi(w.x);
      v2 += bflo(w.y); v3 += bfhi(w.y);
    }
    if (e < end) {
      int s0 = col[e];
      uint2 u = *(const uint2*)(tc + (size_t)s0 * 40);
      v0 += bflo(u.x); v1 += bfhi(u.x);
      v2 += bflo(u.y); v3 += bfhi(u.y);
    }
  }
  const float* bb = bias + 4 * ceff;
  v0 += bb[0]; v1 += bb[1]; v2 += bb[2]; v3 += bb[3];
  float m = act ? fmaxf(fmaxf(v0, v1), fmaxf(v2, v3)) : -__builtin_inff();
#pragma unroll
  for (int off = 8; off; off >>= 1) m = fmaxf(m, __shfl_xor(m, off, 64));
  float ex = act ? (__expf(v0 - m) + __expf(v1 - m) + __expf(v2 - m) + __expf(v3 - m)) : 0.f;
#pragma unroll
  for (int off = 8; off; off >>= 1) ex += __shfl_xor(ex, off, 64);
  if (act) {
    float l = m + __logf(ex);
    float* o = out + (size_t)node * 40 + 4 * c;
    o[0] = v0 - l; o[1] = v1 - l; o[2] = v2 - l; o[3] = v3 - l;
  }
}

// ================= Launch =================

extern "C" void kernel_launch(void* const* d_in, const int* in_sizes, int n_in,
                              void* d_out, int out_size, void* d_ws, size_t ws_size,
                              hipStream_t stream) {
  const float* x  = (const float*)d_in[0];
  const float* W1 = (const float*)d_in[1];
  const float* b1 = (const float*)d_in[2];
  const float* W2 = (const float*)d_in[3];
  const float* b2 = (const float*)d_in[4];
  const float* W3 = (const float*)d_in[5];
  const float* b3 = (const float*)d_in[6];
  const int* edge = (const int*)d_in[7];

  int N = in_sizes[0] / 128;  // 50000
  int E = in_sizes[7] / 2;    // 800000
  const int* srcp = edge;
  const int* dstp = edge + E;

  char* p = (char*)d_ws;
  auto alloc = [&](size_t bytes) {
    char* r = p;
    p += (bytes + 255) & ~size_t(255);
    return r;
  };
  int NB = (N + 255) >> 8;  // 196 buckets of 256 nodes
  int* partial = (int*)alloc((size_t)CB * 256 * 4);
  int* gstart  = (int*)alloc((size_t)(NB + 1) * 4);
  int* gcur    = (int*)alloc((size_t)NB * 4);
  int* row_ptr = (int*)alloc((size_t)(N + 1) * 4);
  int* packed  = (int*)alloc((size_t)E * 4);
  int* col     = (int*)alloc((size_t)E * 4);
  unsigned short* Wp1 = (unsigned short*)alloc(1536 * 8 * 2);
  unsigned short* Wp2 = (unsigned short*)alloc(1152 * 8 * 2);
  unsigned short* Wp3 = (unsigned short*)alloc(576 * 8 * 2);
  unsigned short* Tb  = (unsigned short*)alloc((size_t)N * 96 * 2);   // t1
  unsigned short* T2b = (unsigned short*)alloc((size_t)N * 96 * 2);   // t2
  unsigned short* T3b = (unsigned short*)alloc((size_t)N * 40 * 2);   // t3

  int E4 = E >> 2;
  int nbin = (E4 + ((E & 3) ? 1 : 0) + 255) / 256;
  int GB = ((N + 15) / 16 + 3) / 4;  // gemm1 blocks (4 row-tiles each)
  int FB = (N + 63) / 64;            // fused blocks (64 nodes each)

  // 1: bucket count + W pack
  count_pack<<<CB + 13, 256, 0, stream>>>(dstp, partial, E, W1, W2, W3, Wp1, Wp2, Wp3);
  // 2: scan bucket totals
  scan_kernel<<<1, 256, 0, stream>>>(partial, gstart, gcur, row_ptr, NB, N, E);
  // 3: bin edges + gemm1 (independent halves of one dispatch)
  bin_gemm1<<<nbin + GB, 256, 0, stream>>>(srcp, dstp, gcur, packed, E, NB, nbin,
                                           x, Wp1, Tb, N);
  // 4: per-bucket CSR finalize
  build_local_csr<<<NB, 256, 0, stream>>>(packed, gstart, row_ptr, col, N);
  // 5: t2 = relu(agg(t1)+b1) @ W2
  fused_agg_gemm<6, 96, 96><<<FB, 256, 0, stream>>>(Tb, row_ptr, col, b1, Wp2, T2b, N);
  // 6: t3 = relu(agg(t2)+b2) @ W3
  fused_agg_gemm<3, 40, 40><<<FB, 256, 0, stream>>>(T2b, row_ptr, col, b2, Wp3, T3b, N);
  // 7: out = log_softmax(agg(t3) + b3)
  agg_lsm_bf16<<<(N + 15) / 16, 256, 0, stream>>>(T3b, row_ptr, col, b3, (float*)d_out, N);
}

// Round 7
// 209.786 us; speedup vs baseline: 1.0632x; 1.0632x over previous
//
#include <hip/hip_runtime.h>
#include <math.h>

typedef __attribute__((ext_vector_type(8))) short bf16x8;
typedef __attribute__((ext_vector_type(4))) float f32x4;

__device__ __forceinline__ unsigned short f2bf(float f) {
  unsigned u = __float_as_uint(f);
  u += 0x7fffu + ((u >> 16) & 1u);  // round-to-nearest-even
  return (unsigned short)(u >> 16);
}
__device__ __forceinline__ float bflo(unsigned u) { return __uint_as_float(u << 16); }
__device__ __forceinline__ float bfhi(unsigned u) { return __uint_as_float(u & 0xffff0000u); }

// ================= CSR via two-level bucket binning =================
// Buckets of 256 nodes. packed edge = (d_local<<16)|src. Requires N <= 65536.

constexpr int CB = 64;  // histogram blocks

// Dispatch 1, three independent block roles:
//   [0, CB)        : per-block partial bucket histograms of dst
//   [CB, CB+7)     : pack W2/W3 into MFMA B-fragment order
//   [CB+7, ...)    : gemm1: Tb = bf16(x) @ W1, B-frags built from raw f32 W1
__global__ __launch_bounds__(256) void count_pack_gemm1(
    const int* __restrict__ dst, int* __restrict__ partial, int E,
    const float* __restrict__ W1, const float* __restrict__ W2, const float* __restrict__ W3,
    unsigned short* __restrict__ Wp2, unsigned short* __restrict__ Wp3,
    const float* __restrict__ x, unsigned short* __restrict__ Tb, int N) {
  int tid = threadIdx.x;
  if (blockIdx.x < CB) {
    __shared__ int bkt[256];
    bkt[tid] = 0;
    __syncthreads();
    int E4 = E >> 2;
    const int4* d4 = (const int4*)dst;
    for (int i = blockIdx.x * 256 + tid; i < E4; i += CB * 256) {
      int4 d = d4[i];
      atomicAdd(&bkt[d.x >> 8], 1);
      atomicAdd(&bkt[d.y >> 8], 1);
      atomicAdd(&bkt[d.z >> 8], 1);
      atomicAdd(&bkt[d.w >> 8], 1);
    }
    if (blockIdx.x == 0 && tid < (E & 3)) atomicAdd(&bkt[dst[E4 * 4 + tid] >> 8], 1);
    __syncthreads();
    partial[blockIdx.x * 256 + tid] = bkt[tid];
    return;
  }
  if (blockIdx.x < CB + 7) {
    // Fragment (s,ct): lane l holds B[k=s*32+(l>>4)*8+j][col=ct*16+(l&15)], j=0..7.
    int gid = (blockIdx.x - CB) * 256 + tid;
    const float* W;
    unsigned short* Wp;
    int t, NCTT, M, MV;
    if (gid < 1152) {           // W2: 3 ksteps * 6 coltiles * 64 lanes
      W = W2; Wp = Wp2; t = gid; NCTT = 6; M = 96; MV = 96;
    } else if (gid < 1728) {    // W3: 3 * 3 * 64 (cols >= 40 zero-padded)
      W = W3; Wp = Wp3; t = gid - 1152; NCTT = 3; M = 40; MV = 40;
    } else {
      return;
    }
    int lane = t & 63;
    int frag = t >> 6;
    int s = frag / NCTT;
    int ct = frag - s * NCTT;
    int colv = ct * 16 + (lane & 15);
    int k0 = s * 32 + (lane >> 4) * 8;
    union { unsigned short s[8]; uint4 u; } pk;
#pragma unroll
    for (int j = 0; j < 8; ++j) {
      float v = (colv < MV) ? W[(k0 + j) * M + colv] : 0.f;
      pk.s[j] = f2bf(v);
    }
    ((uint4*)Wp)[t] = pk.u;
    return;
  }
  // ---- gemm1: 16 rows x 96 cols per wave, KSTEPS=4, raw-W1 fragments ----
  int bgx = blockIdx.x - CB - 7;
  int wid = tid >> 6;
  int lane = tid & 63;
  int rt = bgx * 4 + wid;
  if (rt * 16 >= N) return;
  int quad = lane >> 4;
  int lm = lane & 15;
  bf16x8 bfrag[4][6];
#pragma unroll
  for (int s = 0; s < 4; ++s)
#pragma unroll
    for (int c = 0; c < 6; ++c) {
      union { unsigned short s[8]; bf16x8 v; } bu;
      int k0 = s * 32 + quad * 8;
      int colv = c * 16 + lm;
#pragma unroll
      for (int j = 0; j < 8; ++j) bu.s[j] = f2bf(W1[(k0 + j) * 96 + colv]);
      bfrag[s][c] = bu.v;
    }
  f32x4 acc[6];
#pragma unroll
  for (int c = 0; c < 6; ++c) acc[c] = (f32x4){0.f, 0.f, 0.f, 0.f};
  int row = rt * 16 + lm;
  if (row >= N) row = N - 1;  // safe dup read; epilogue guards rows
#pragma unroll
  for (int s = 0; s < 4; ++s) {
    int k0 = s * 32 + quad * 8;
    const float* Af = x + (size_t)row * 128 + k0;
    float4 x0 = *(const float4*)(Af);
    float4 x1 = *(const float4*)(Af + 4);
    union { unsigned short s[8]; bf16x8 v; } au;
    au.s[0] = f2bf(x0.x); au.s[1] = f2bf(x0.y); au.s[2] = f2bf(x0.z); au.s[3] = f2bf(x0.w);
    au.s[4] = f2bf(x1.x); au.s[5] = f2bf(x1.y); au.s[6] = f2bf(x1.z); au.s[7] = f2bf(x1.w);
#pragma unroll
    for (int c = 0; c < 6; ++c)
      acc[c] = __builtin_amdgcn_mfma_f32_16x16x32_bf16(au.v, bfrag[s][c], acc[c], 0, 0, 0);
  }
#pragma unroll
  for (int c = 0; c < 6; ++c) {
    int colv = c * 16 + lm;
#pragma unroll
    for (int r = 0; r < 4; ++r) {
      int orow = rt * 16 + quad * 4 + r;
      if (orow < N) Tb[(size_t)orow * 96 + colv] = f2bf(acc[c][r]);
    }
  }
}

// One block: reduce partials + exclusive scan over NB buckets.
__global__ __launch_bounds__(256) void scan_kernel(const int* __restrict__ partial,
                                                   int* __restrict__ gstart,
                                                   int* __restrict__ gcur,
                                                   int* __restrict__ row_ptr,
                                                   int NB, int N, int E) {
  int tid = threadIdx.x;
  int s = 0;
#pragma unroll 8
  for (int i = 0; i < CB; ++i) s += partial[i * 256 + tid];
  __shared__ int sm[256];
  sm[tid] = s;
  __syncthreads();
  for (int off = 1; off < 256; off <<= 1) {
    int u = (tid >= off) ? sm[tid - off] : 0;
    __syncthreads();
    sm[tid] += u;
    __syncthreads();
  }
  int excl = sm[tid] - s;
  if (tid < NB) { gstart[tid] = excl; gcur[tid] = excl; }
  if (tid == NB - 1) gstart[NB] = sm[tid];
  if (tid == 0) row_ptr[N] = E;
}

// Bin edges into bucket-contiguous packed array.
__global__ __launch_bounds__(256) void bin_edges(const int* __restrict__ src,
                                                 const int* __restrict__ dst,
                                                 int* __restrict__ gcur,
                                                 int* __restrict__ packed, int E, int NB) {
  __shared__ int lcnt[256];
  __shared__ int gbase[256];
  int tid = threadIdx.x;
  lcnt[tid] = 0;
  __syncthreads();
  int idx = blockIdx.x * 256 + tid;  // int4 index
  int E4 = E >> 2;
  int sv[4], dv[4], lv[4];
  int cnt = 0;
  if (idx < E4) {
    int4 s4 = ((const int4*)src)[idx];
    int4 d4 = ((const int4*)dst)[idx];
    sv[0] = s4.x; sv[1] = s4.y; sv[2] = s4.z; sv[3] = s4.w;
    dv[0] = d4.x; dv[1] = d4.y; dv[2] = d4.z; dv[3] = d4.w;
    cnt = 4;
  } else if (idx == E4 && (E & 3)) {
    int tl = E & 3;
    for (int i = 0; i < tl; ++i) { sv[i] = src[E4 * 4 + i]; dv[i] = dst[E4 * 4 + i]; }
    cnt = tl;
  }
  for (int i = 0; i < cnt; ++i) lv[i] = atomicAdd(&lcnt[dv[i] >> 8], 1);
  __syncthreads();
  if (tid < NB) gbase[tid] = atomicAdd(&gcur[tid], lcnt[tid]);
  __syncthreads();
  for (int i = 0; i < cnt; ++i) {
    int b = dv[i] >> 8;
    packed[gbase[b] + lv[i]] = ((dv[i] & 255) << 16) | (sv[i] & 0xffff);
  }
}

// One block per 256-node bucket: local count -> local scan -> row_ptr + col.
__global__ __launch_bounds__(256) void build_local_csr(const int* __restrict__ packed,
                                                       const int* __restrict__ gstart,
                                                       int* __restrict__ row_ptr,
                                                       int* __restrict__ col, int N) {
  __shared__ int cnt[256];
  __shared__ int sm[256];
  int b = blockIdx.x, tid = threadIdx.x;
  int gs = gstart[b], ge = gstart[b + 1];
  int me = ge - gs;
  int node0 = b << 8;
  int RL = N - node0;
  if (RL > 256) RL = 256;
  cnt[tid] = 0;
  __syncthreads();
  for (int i = tid; i < me; i += 256) atomicAdd(&cnt[packed[gs + i] >> 16], 1);
  __syncthreads();
  int v = cnt[tid];
  sm[tid] = v;
  __syncthreads();
  for (int off = 1; off < 256; off <<= 1) {
    int u = (tid >= off) ? sm[tid - off] : 0;
    __syncthreads();
    sm[tid] += u;
    __syncthreads();
  }
  int excl = gs + sm[tid] - v;
  __syncthreads();
  cnt[tid] = excl;  // repurpose as cursor
  if (tid < RL) row_ptr[node0 + tid] = excl;
  __syncthreads();
  for (int i = tid; i < me; i += 256) {
    int pk = packed[gs + i];
    int p = atomicAdd(&cnt[pk >> 16], 1);
    col[p] = pk & 0xffff;
  }
}

// ================= Fused aggregation + GEMM (col staged in LDS) =================
// Block owns 64 nodes. Stage the block's contiguous col range + row_ptr slice in
// LDS (kills the 12x-redundant global col loads). Phase A: h=relu(agg+bias) ->
// LDS (stride 104). Phase B: 4 waves x 16-row MFMA tiles, h @ W.

template <int NCT, int MOUT, int MVALID>
__global__ __launch_bounds__(256) void fused_agg_gemm(const unsigned short* __restrict__ tin,
                                                      const int* __restrict__ row_ptr,
                                                      const int* __restrict__ col,
                                                      const float* __restrict__ bias,
                                                      const unsigned short* __restrict__ Wp,
                                                      unsigned short* __restrict__ outp, int N) {
  constexpr int LST = 104;   // bf16 units per LDS row
  constexpr int CAP = 2048;  // staged edges (mean 1024, ~32 sigma headroom)
  __shared__ unsigned short sH[64 * LST];
  __shared__ int scol[CAP];
  __shared__ int srp[65];
  int tid = threadIdx.x;
  int node0 = blockIdx.x * 64;
  int nloc = N - node0;
  if (nloc > 64) nloc = 64;
  if (tid <= nloc) srp[tid] = row_ptr[node0 + tid];
  __syncthreads();
  int gs = srp[0];
  int me = srp[nloc] - gs;
  for (int i = tid; i < me && i < CAP; i += 256) scol[i] = col[gs + i];
  __syncthreads();

  // ---- Phase A: aggregate 64 nodes x 12 chunks of 8 bf16 ----
#pragma unroll
  for (int it = 0; it < 3; ++it) {
    int u = tid + it * 256;
    int nl = u / 12;
    int c = u - nl * 12;
    if (nl < nloc) {
      int beg = srp[nl] - gs;
      int end = srp[nl + 1] - gs;
      const unsigned short* tc = tin + 8 * c;
      float a0 = 0.f, a1 = 0.f, a2 = 0.f, a3 = 0.f, a4 = 0.f, a5 = 0.f, a6 = 0.f, a7 = 0.f;
      int e = beg;
      for (; e + 1 < end; e += 2) {
        int s0 = (e < CAP) ? scol[e] : col[gs + e];
        int s1 = (e + 1 < CAP) ? scol[e + 1] : col[gs + e + 1];
        uint4 u4 = *(const uint4*)(tc + (size_t)s0 * 96);
        uint4 w4 = *(const uint4*)(tc + (size_t)s1 * 96);
        a0 += bflo(u4.x); a1 += bfhi(u4.x);
        a2 += bflo(u4.y); a3 += bfhi(u4.y);
        a4 += bflo(u4.z); a5 += bfhi(u4.z);
        a6 += bflo(u4.w); a7 += bfhi(u4.w);
        a0 += bflo(w4.x); a1 += bfhi(w4.x);
        a2 += bflo(w4.y); a3 += bfhi(w4.y);
        a4 += bflo(w4.z); a5 += bfhi(w4.z);
        a6 += bflo(w4.w); a7 += bfhi(w4.w);
      }
      if (e < end) {
        int s0 = (e < CAP) ? scol[e] : col[gs + e];
        uint4 u4 = *(const uint4*)(tc + (size_t)s0 * 96);
        a0 += bflo(u4.x); a1 += bfhi(u4.x);
        a2 += bflo(u4.y); a3 += bfhi(u4.y);
        a4 += bflo(u4.z); a5 += bfhi(u4.z);
        a6 += bflo(u4.w); a7 += bfhi(u4.w);
      }
      const float* b = bias + 8 * c;
      union { unsigned short s[8]; uint4 u; } pk;
      pk.s[0] = f2bf(fmaxf(a0 + b[0], 0.f));
      pk.s[1] = f2bf(fmaxf(a1 + b[1], 0.f));
      pk.s[2] = f2bf(fmaxf(a2 + b[2], 0.f));
      pk.s[3] = f2bf(fmaxf(a3 + b[3], 0.f));
      pk.s[4] = f2bf(fmaxf(a4 + b[4], 0.f));
      pk.s[5] = f2bf(fmaxf(a5 + b[5], 0.f));
      pk.s[6] = f2bf(fmaxf(a6 + b[6], 0.f));
      pk.s[7] = f2bf(fmaxf(a7 + b[7], 0.f));
      *(uint4*)&sH[nl * LST + c * 8] = pk.u;
    }
  }
  __syncthreads();

  // ---- Phase B: MFMA tile per wave ----
  int wid = tid >> 6;
  int lane = tid & 63;
  int rt16 = wid * 16;
  if (node0 + rt16 >= N) return;
  int quad = lane >> 4;
  int lm = lane & 15;
  union BU { uint4 u; bf16x8 v; };
  bf16x8 bfrag[3][NCT];
  const uint4* wp4 = (const uint4*)Wp;
#pragma unroll
  for (int s = 0; s < 3; ++s)
#pragma unroll
    for (int c = 0; c < NCT; ++c) {
      BU bu;
      bu.u = wp4[(s * NCT + c) * 64 + lane];
      bfrag[s][c] = bu.v;
    }
  f32x4 acc[NCT];
#pragma unroll
  for (int c = 0; c < NCT; ++c) acc[c] = (f32x4){0.f, 0.f, 0.f, 0.f};
#pragma unroll
  for (int s = 0; s < 3; ++s) {
    BU au;
    au.u = *(const uint4*)&sH[(rt16 + lm) * LST + s * 32 + quad * 8];
#pragma unroll
    for (int c = 0; c < NCT; ++c)
      acc[c] = __builtin_amdgcn_mfma_f32_16x16x32_bf16(au.v, bfrag[s][c], acc[c], 0, 0, 0);
  }
#pragma unroll
  for (int c = 0; c < NCT; ++c) {
    int colv = c * 16 + lm;
    if (colv >= MVALID) continue;
#pragma unroll
    for (int r = 0; r < 4; ++r) {
      int orow = node0 + rt16 + quad * 4 + r;
      if (orow < N) outp[(size_t)orow * MOUT + colv] = f2bf(acc[c][r]);
    }
  }
}

// Layer-3 aggregation (bf16 in) + bias + log_softmax, col staged in LDS.
// Block = 16 nodes; 16-lane group per node; lanes 0..9 hold 4 classes each.
__global__ __launch_bounds__(256) void agg_lsm_bf16(const unsigned short* __restrict__ t,
                                                    const int* __restrict__ row_ptr,
                                                    const int* __restrict__ col,
                                                    const float* __restrict__ bias,
                                                    float* __restrict__ out, int N) {
  constexpr int CAPL = 1024;  // staged edges (mean 256)
  __shared__ int scol[CAPL];
  __shared__ int srp[17];
  int tid = threadIdx.x;
  int node0 = blockIdx.x * 16;
  int nloc = N - node0;
  if (nloc > 16) nloc = 16;
  if (tid <= nloc) srp[tid] = row_ptr[node0 + tid];
  __syncthreads();
  int gs = srp[0];
  int me = srp[nloc] - gs;
  for (int i = tid; i < me && i < CAPL; i += 256) scol[i] = col[gs + i];
  __syncthreads();

  int nl = tid >> 4;
  int c = tid & 15;  // 0..9 active
  bool act = (c < 10) && (nl < nloc);
  int ceff = (c < 10) ? c : 0;
  const unsigned short* tc = t + 4 * ceff;
  float v0 = 0.f, v1 = 0.f, v2 = 0.f, v3 = 0.f;
  if (act) {
    int beg = srp[nl] - gs;
    int end = srp[nl + 1] - gs;
    int e = beg;
    for (; e + 1 < end; e += 2) {
      int s0 = (e < CAPL) ? scol[e] : col[gs + e];
      int s1 = (e + 1 < CAPL) ? scol[e + 1] : col[gs + e + 1];
      uint2 u = *(const uint2*)(tc + (size_t)s0 * 40);
      uint2 w = *(const uint2*)(tc + (size_t)s1 * 40);
      v0 += bflo(u.x); v1 += bfhi(u.x);
      v2 += bflo(u.y); v3 += bfhi(u.y);
      v0 += bflo(w.x); v1 += bfhi(w.x);
      v2 += bflo(w.y); v3 += bfhi(w.y);
    }
    if (e < end) {
      int s0 = (e < CAPL) ? scol[e] : col[gs + e];
      uint2 u = *(const uint2*)(tc + (size_t)s0 * 40);
      v0 += bflo(u.x); v1 += bfhi(u.x);
      v2 += bflo(u.y); v3 += bfhi(u.y);
    }
  }
  const float* bb = bias + 4 * ceff;
  v0 += bb[0]; v1 += bb[1]; v2 += bb[2]; v3 += bb[3];
  float m = act ? fmaxf(fmaxf(v0, v1), fmaxf(v2, v3)) : -__builtin_inff();
#pragma unroll
  for (int off = 8; off; off >>= 1) m = fmaxf(m, __shfl_xor(m, off, 64));
  float ex = act ? (__expf(v0 - m) + __expf(v1 - m) + __expf(v2 - m) + __expf(v3 - m)) : 0.f;
#pragma unroll
  for (int off = 8; off; off >>= 1) ex += __shfl_xor(ex, off, 64);
  if (act) {
    int node = node0 + nl;
    float l = m + __logf(ex);
    float* o = out + (size_t)node * 40 + 4 * c;
    o[0] = v0 - l; o[1] = v1 - l; o[2] = v2 - l; o[3] = v3 - l;
  }
}

// ================= Launch =================

extern "C" void kernel_launch(void* const* d_in, const int* in_sizes, int n_in,
                              void* d_out, int out_size, void* d_ws, size_t ws_size,
                              hipStream_t stream) {
  const float* x  = (const float*)d_in[0];
  const float* W1 = (const float*)d_in[1];
  const float* b1 = (const float*)d_in[2];
  const float* W2 = (const float*)d_in[3];
  const float* b2 = (const float*)d_in[4];
  const float* W3 = (const float*)d_in[5];
  const float* b3 = (const float*)d_in[6];
  const int* edge = (const int*)d_in[7];

  int N = in_sizes[0] / 128;  // 50000
  int E = in_sizes[7] / 2;    // 800000
  const int* srcp = edge;
  const int* dstp = edge + E;

  char* p = (char*)d_ws;
  auto alloc = [&](size_t bytes) {
    char* r = p;
    p += (bytes + 255) & ~size_t(255);
    return r;
  };
  int NB = (N + 255) >> 8;  // 196 buckets of 256 nodes
  int* partial = (int*)alloc((size_t)CB * 256 * 4);
  int* gstart  = (int*)alloc((size_t)(NB + 1) * 4);
  int* gcur    = (int*)alloc((size_t)NB * 4);
  int* row_ptr = (int*)alloc((size_t)(N + 1) * 4);
  int* packed  = (int*)alloc((size_t)E * 4);
  int* col     = (int*)alloc((size_t)E * 4);
  unsigned short* Wp2 = (unsigned short*)alloc(1152 * 8 * 2);
  unsigned short* Wp3 = (unsigned short*)alloc(576 * 8 * 2);
  unsigned short* Tb  = (unsigned short*)alloc((size_t)N * 96 * 2);   // t1
  unsigned short* T2b = (unsigned short*)alloc((size_t)N * 96 * 2);   // t2
  unsigned short* T3b = (unsigned short*)alloc((size_t)N * 40 * 2);   // t3

  int E4 = E >> 2;
  int nbin = (E4 + ((E & 3) ? 1 : 0) + 255) / 256;
  int GB = ((N + 15) / 16 + 3) / 4;  // gemm1 blocks (4 row-tiles each)
  int FB = (N + 63) / 64;            // fused blocks (64 nodes each)

  // 1: bucket count + W2/W3 pack + gemm1 (all independent)
  count_pack_gemm1<<<CB + 7 + GB, 256, 0, stream>>>(dstp, partial, E, W1, W2, W3,
                                                    Wp2, Wp3, x, Tb, N);
  // 2: scan bucket totals
  scan_kernel<<<1, 256, 0, stream>>>(partial, gstart, gcur, row_ptr, NB, N, E);
  // 3: bin edges
  bin_edges<<<nbin, 256, 0, stream>>>(srcp, dstp, gcur, packed, E, NB);
  // 4: per-bucket CSR finalize
  build_local_csr<<<NB, 256, 0, stream>>>(packed, gstart, row_ptr, col, N);
  // 5: t2 = relu(agg(t1)+b1) @ W2
  fused_agg_gemm<6, 96, 96><<<FB, 256, 0, stream>>>(Tb, row_ptr, col, b1, Wp2, T2b, N);
  // 6: t3 = relu(agg(t2)+b2) @ W3
  fused_agg_gemm<3, 40, 40><<<FB, 256, 0, stream>>>(T2b, row_ptr, col, b2, Wp3, T3b, N);
  // 7: out = log_softmax(agg(t3) + b3)
  agg_lsm_bf16<<<(N + 15) / 16, 256, 0, stream>>>(T3b, row_ptr, col, b3, (float*)d_out, N);
}

// Round 8
// 203.150 us; speedup vs baseline: 1.0979x; 1.0327x over previous
//
#include <hip/hip_runtime.h>
#include <math.h>

typedef __attribute__((ext_vector_type(8))) short bf16x8;
typedef __attribute__((ext_vector_type(4))) float f32x4;

__device__ __forceinline__ unsigned short f2bf(float f) {
  unsigned u = __float_as_uint(f);
  u += 0x7fffu + ((u >> 16) & 1u);  // round-to-nearest-even
  return (unsigned short)(u >> 16);
}
__device__ __forceinline__ float bflo(unsigned u) { return __uint_as_float(u << 16); }
__device__ __forceinline__ float bfhi(unsigned u) { return __uint_as_float(u & 0xffff0000u); }

// ================= CSR via two-level bucket binning =================
// Buckets of 256 nodes. packed edge = (d_local<<16)|src. Requires N <= 65536.

constexpr int CB = 64;  // histogram blocks

// Dispatch 1: [0,CB) histogram partials; [CB,CB+13) pack W1/W2/W3 to MFMA
// B-fragment order. Fragment (s,ct): lane l holds
// B[k=s*32+(l>>4)*8+j][col=ct*16+(l&15)], j=0..7, 8 contiguous bf16.
__global__ __launch_bounds__(256) void count_pack(const int* __restrict__ dst,
                                                  int* __restrict__ partial, int E,
                                                  const float* __restrict__ W1,
                                                  const float* __restrict__ W2,
                                                  const float* __restrict__ W3,
                                                  unsigned short* __restrict__ Wp1,
                                                  unsigned short* __restrict__ Wp2,
                                                  unsigned short* __restrict__ Wp3) {
  int tid = threadIdx.x;
  if (blockIdx.x < CB) {
    __shared__ int bkt[256];
    bkt[tid] = 0;
    __syncthreads();
    int E4 = E >> 2;
    const int4* d4 = (const int4*)dst;
    for (int i = blockIdx.x * 256 + tid; i < E4; i += CB * 256) {
      int4 d = d4[i];
      atomicAdd(&bkt[d.x >> 8], 1);
      atomicAdd(&bkt[d.y >> 8], 1);
      atomicAdd(&bkt[d.z >> 8], 1);
      atomicAdd(&bkt[d.w >> 8], 1);
    }
    if (blockIdx.x == 0 && tid < (E & 3)) atomicAdd(&bkt[dst[E4 * 4 + tid] >> 8], 1);
    __syncthreads();
    partial[blockIdx.x * 256 + tid] = bkt[tid];
    return;
  }
  int gid = (blockIdx.x - CB) * 256 + tid;
  const float* W;
  unsigned short* Wp;
  int t, NCTT, M, MV;
  if (gid < 1536) {            // W1: 4 ksteps * 6 coltiles * 64 lanes
    W = W1; Wp = Wp1; t = gid; NCTT = 6; M = 96; MV = 96;
  } else if (gid < 2688) {     // W2: 3 * 6 * 64
    W = W2; Wp = Wp2; t = gid - 1536; NCTT = 6; M = 96; MV = 96;
  } else if (gid < 3264) {     // W3: 3 * 3 * 64 (cols >= 40 zero-padded)
    W = W3; Wp = Wp3; t = gid - 2688; NCTT = 3; M = 40; MV = 40;
  } else {
    return;
  }
  int lane = t & 63;
  int frag = t >> 6;
  int s = frag / NCTT;
  int ct = frag - s * NCTT;
  int colv = ct * 16 + (lane & 15);
  int k0 = s * 32 + (lane >> 4) * 8;
  union { unsigned short s[8]; uint4 u; } pk;
#pragma unroll
  for (int j = 0; j < 8; ++j) {
    float v = (colv < MV) ? W[(k0 + j) * M + colv] : 0.f;
    pk.s[j] = f2bf(v);
  }
  ((uint4*)Wp)[t] = pk.u;
}

// One block: reduce partials + exclusive scan over NB buckets.
__global__ __launch_bounds__(256) void scan_kernel(const int* __restrict__ partial,
                                                   int* __restrict__ gstart,
                                                   int* __restrict__ gcur,
                                                   int* __restrict__ row_ptr,
                                                   int NB, int N, int E) {
  int tid = threadIdx.x;
  int s = 0;
#pragma unroll 8
  for (int i = 0; i < CB; ++i) s += partial[i * 256 + tid];
  __shared__ int sm[256];
  sm[tid] = s;
  __syncthreads();
  for (int off = 1; off < 256; off <<= 1) {
    int u = (tid >= off) ? sm[tid - off] : 0;
    __syncthreads();
    sm[tid] += u;
    __syncthreads();
  }
  int excl = sm[tid] - s;
  if (tid < NB) { gstart[tid] = excl; gcur[tid] = excl; }
  if (tid == NB - 1) gstart[NB] = sm[tid];
  if (tid == 0) row_ptr[N] = E;
}

// Dispatch 3: [0,NBIN) bin edges; [NBIN,..) gemm1 Tb = bf16(x) @ W1 using
// packed Wp1 (written in dispatch 1 — race-free). Independent halves overlap.
__global__ __launch_bounds__(256) void bin_gemm1(const int* __restrict__ src,
                                                 const int* __restrict__ dst,
                                                 int* __restrict__ gcur,
                                                 int* __restrict__ packed, int E, int NB,
                                                 int NBIN, const float* __restrict__ x,
                                                 const unsigned short* __restrict__ Wp1,
                                                 unsigned short* __restrict__ Tb, int N) {
  int tid = threadIdx.x;
  if (blockIdx.x < NBIN) {
    __shared__ int lcnt[256];
    __shared__ int gbase[256];
    lcnt[tid] = 0;
    __syncthreads();
    int idx = blockIdx.x * 256 + tid;  // int4 index
    int E4 = E >> 2;
    int sv[4], dv[4], lv[4];
    int cnt = 0;
    if (idx < E4) {
      int4 s4 = ((const int4*)src)[idx];
      int4 d4 = ((const int4*)dst)[idx];
      sv[0] = s4.x; sv[1] = s4.y; sv[2] = s4.z; sv[3] = s4.w;
      dv[0] = d4.x; dv[1] = d4.y; dv[2] = d4.z; dv[3] = d4.w;
      cnt = 4;
    } else if (idx == E4 && (E & 3)) {
      int tl = E & 3;
      for (int i = 0; i < tl; ++i) { sv[i] = src[E4 * 4 + i]; dv[i] = dst[E4 * 4 + i]; }
      cnt = tl;
    }
    for (int i = 0; i < cnt; ++i) lv[i] = atomicAdd(&lcnt[dv[i] >> 8], 1);
    __syncthreads();
    if (tid < NB) gbase[tid] = atomicAdd(&gcur[tid], lcnt[tid]);
    __syncthreads();
    for (int i = 0; i < cnt; ++i) {
      int b = dv[i] >> 8;
      packed[gbase[b] + lv[i]] = ((dv[i] & 255) << 16) | (sv[i] & 0xffff);
    }
    return;
  }
  // ---- gemm1: 16 rows x 96 cols per wave, KSTEPS=4 ----
  int bx = blockIdx.x - NBIN;
  int wid = tid >> 6;
  int lane = tid & 63;
  int rt = bx * 4 + wid;
  if (rt * 16 >= N) return;
  int quad = lane >> 4;
  int lm = lane & 15;
  union BU { uint4 u; bf16x8 v; };
  f32x4 acc[6];
#pragma unroll
  for (int c = 0; c < 6; ++c) acc[c] = (f32x4){0.f, 0.f, 0.f, 0.f};
  int row = rt * 16 + lm;
  if (row >= N) row = N - 1;  // safe dup read; epilogue guards rows
  const uint4* wp4 = (const uint4*)Wp1;
#pragma unroll
  for (int s = 0; s < 4; ++s) {
    int k0 = s * 32 + quad * 8;
    const float* Af = x + (size_t)row * 128 + k0;
    float4 x0 = *(const float4*)(Af);
    float4 x1 = *(const float4*)(Af + 4);
    union { unsigned short s[8]; bf16x8 v; } au;
    au.s[0] = f2bf(x0.x); au.s[1] = f2bf(x0.y); au.s[2] = f2bf(x0.z); au.s[3] = f2bf(x0.w);
    au.s[4] = f2bf(x1.x); au.s[5] = f2bf(x1.y); au.s[6] = f2bf(x1.z); au.s[7] = f2bf(x1.w);
#pragma unroll
    for (int c = 0; c < 6; ++c) {
      BU bu;
      bu.u = wp4[(s * 6 + c) * 64 + lane];
      acc[c] = __builtin_amdgcn_mfma_f32_16x16x32_bf16(au.v, bu.v, acc[c], 0, 0, 0);
    }
  }
#pragma unroll
  for (int c = 0; c < 6; ++c) {
    int colv = c * 16 + lm;
#pragma unroll
    for (int r = 0; r < 4; ++r) {
      int orow = rt * 16 + quad * 4 + r;
      if (orow < N) Tb[(size_t)orow * 96 + colv] = f2bf(acc[c][r]);
    }
  }
}

// One block per 256-node bucket: local count -> local scan -> row_ptr + col.
__global__ __launch_bounds__(256) void build_local_csr(const int* __restrict__ packed,
                                                       const int* __restrict__ gstart,
                                                       int* __restrict__ row_ptr,
                                                       int* __restrict__ col, int N) {
  __shared__ int cnt[256];
  __shared__ int sm[256];
  int b = blockIdx.x, tid = threadIdx.x;
  int gs = gstart[b], ge = gstart[b + 1];
  int me = ge - gs;
  int node0 = b << 8;
  int RL = N - node0;
  if (RL > 256) RL = 256;
  cnt[tid] = 0;
  __syncthreads();
  for (int i = tid; i < me; i += 256) atomicAdd(&cnt[packed[gs + i] >> 16], 1);
  __syncthreads();
  int v = cnt[tid];
  sm[tid] = v;
  __syncthreads();
  for (int off = 1; off < 256; off <<= 1) {
    int u = (tid >= off) ? sm[tid - off] : 0;
    __syncthreads();
    sm[tid] += u;
    __syncthreads();
  }
  int excl = gs + sm[tid] - v;
  __syncthreads();
  cnt[tid] = excl;  // repurpose as cursor
  if (tid < RL) row_ptr[node0 + tid] = excl;
  __syncthreads();
  for (int i = tid; i < me; i += 256) {
    int pk = packed[gs + i];
    int p = atomicAdd(&cnt[pk >> 16], 1);
    col[p] = pk & 0xffff;
  }
}

// ================= Fused aggregation + GEMM =================
// Block owns 64 nodes; col + row_ptr staged in LDS. Phase A: h=relu(agg+bias)
// -> LDS (stride 104), gather unrolled x4 for MLP. Phase B: 4 waves x 16-row
// MFMA tiles; B-frags reloaded from L2-hot Wp per k-step to keep VGPR <= ~85
// (launch_bounds 6 blocks/CU: gather phase occupancy is the binding resource).

template <int NCT, int MOUT, int MVALID>
__global__ __launch_bounds__(256, 6) void fused_agg_gemm(
    const unsigned short* __restrict__ tin, const int* __restrict__ row_ptr,
    const int* __restrict__ col, const float* __restrict__ bias,
    const unsigned short* __restrict__ Wp, unsigned short* __restrict__ outp, int N) {
  constexpr int LST = 104;   // bf16 units per LDS row
  constexpr int CAP = 2048;  // staged edges (mean 1024, ~32 sigma headroom)
  __shared__ unsigned short sH[64 * LST];
  __shared__ int scol[CAP];
  __shared__ int srp[65];
  int tid = threadIdx.x;
  int node0 = blockIdx.x * 64;
  int nloc = N - node0;
  if (nloc > 64) nloc = 64;
  if (tid <= nloc) srp[tid] = row_ptr[node0 + tid];
  __syncthreads();
  int gs = srp[0];
  int me = srp[nloc] - gs;
  for (int i = tid; i < me && i < CAP; i += 256) scol[i] = col[gs + i];
  __syncthreads();

  // ---- Phase A: aggregate 64 nodes x 12 chunks of 8 bf16, unroll x4 ----
#pragma unroll
  for (int it = 0; it < 3; ++it) {
    int u = tid + it * 256;
    int nl = u / 12;
    int c = u - nl * 12;
    if (nl < nloc) {
      int beg = srp[nl] - gs;
      int end = srp[nl + 1] - gs;
      const unsigned short* tc = tin + 8 * c;
      float a0 = 0.f, a1 = 0.f, a2 = 0.f, a3 = 0.f, a4 = 0.f, a5 = 0.f, a6 = 0.f, a7 = 0.f;
      int e = beg;
      for (; e + 3 < end; e += 4) {
        int s0 = (e < CAP) ? scol[e] : col[gs + e];
        int s1 = (e + 1 < CAP) ? scol[e + 1] : col[gs + e + 1];
        int s2 = (e + 2 < CAP) ? scol[e + 2] : col[gs + e + 2];
        int s3 = (e + 3 < CAP) ? scol[e + 3] : col[gs + e + 3];
        uint4 u0 = *(const uint4*)(tc + (size_t)s0 * 96);
        uint4 u1 = *(const uint4*)(tc + (size_t)s1 * 96);
        uint4 u2 = *(const uint4*)(tc + (size_t)s2 * 96);
        uint4 u3 = *(const uint4*)(tc + (size_t)s3 * 96);
        a0 += bflo(u0.x); a1 += bfhi(u0.x); a2 += bflo(u0.y); a3 += bfhi(u0.y);
        a4 += bflo(u0.z); a5 += bfhi(u0.z); a6 += bflo(u0.w); a7 += bfhi(u0.w);
        a0 += bflo(u1.x); a1 += bfhi(u1.x); a2 += bflo(u1.y); a3 += bfhi(u1.y);
        a4 += bflo(u1.z); a5 += bfhi(u1.z); a6 += bflo(u1.w); a7 += bfhi(u1.w);
        a0 += bflo(u2.x); a1 += bfhi(u2.x); a2 += bflo(u2.y); a3 += bfhi(u2.y);
        a4 += bflo(u2.z); a5 += bfhi(u2.z); a6 += bflo(u2.w); a7 += bfhi(u2.w);
        a0 += bflo(u3.x); a1 += bfhi(u3.x); a2 += bflo(u3.y); a3 += bfhi(u3.y);
        a4 += bflo(u3.z); a5 += bfhi(u3.z); a6 += bflo(u3.w); a7 += bfhi(u3.w);
      }
      for (; e < end; ++e) {
        int s0 = (e < CAP) ? scol[e] : col[gs + e];
        uint4 u4 = *(const uint4*)(tc + (size_t)s0 * 96);
        a0 += bflo(u4.x); a1 += bfhi(u4.x); a2 += bflo(u4.y); a3 += bfhi(u4.y);
        a4 += bflo(u4.z); a5 += bfhi(u4.z); a6 += bflo(u4.w); a7 += bfhi(u4.w);
      }
      const float* b = bias + 8 * c;
      union { unsigned short s[8]; uint4 u; } pk;
      pk.s[0] = f2bf(fmaxf(a0 + b[0], 0.f));
      pk.s[1] = f2bf(fmaxf(a1 + b[1], 0.f));
      pk.s[2] = f2bf(fmaxf(a2 + b[2], 0.f));
      pk.s[3] = f2bf(fmaxf(a3 + b[3], 0.f));
      pk.s[4] = f2bf(fmaxf(a4 + b[4], 0.f));
      pk.s[5] = f2bf(fmaxf(a5 + b[5], 0.f));
      pk.s[6] = f2bf(fmaxf(a6 + b[6], 0.f));
      pk.s[7] = f2bf(fmaxf(a7 + b[7], 0.f));
      *(uint4*)&sH[nl * LST + c * 8] = pk.u;
    }
  }
  __syncthreads();

  // ---- Phase B: MFMA tile per wave; per-step B-frag reload ----
  int wid = tid >> 6;
  int lane = tid & 63;
  int rt16 = wid * 16;
  if (node0 + rt16 >= N) return;
  int quad = lane >> 4;
  int lm = lane & 15;
  union BU { uint4 u; bf16x8 v; };
  f32x4 acc[NCT];
#pragma unroll
  for (int c = 0; c < NCT; ++c) acc[c] = (f32x4){0.f, 0.f, 0.f, 0.f};
  const uint4* wp4 = (const uint4*)Wp;
#pragma unroll
  for (int s = 0; s < 3; ++s) {
    BU au;
    au.u = *(const uint4*)&sH[(rt16 + lm) * LST + s * 32 + quad * 8];
#pragma unroll
    for (int c = 0; c < NCT; ++c) {
      BU bu;
      bu.u = wp4[(s * NCT + c) * 64 + lane];
      acc[c] = __builtin_amdgcn_mfma_f32_16x16x32_bf16(au.v, bu.v, acc[c], 0, 0, 0);
    }
  }
#pragma unroll
  for (int c = 0; c < NCT; ++c) {
    int colv = c * 16 + lm;
    if (colv >= MVALID) continue;
#pragma unroll
    for (int r = 0; r < 4; ++r) {
      int orow = node0 + rt16 + quad * 4 + r;
      if (orow < N) outp[(size_t)orow * MOUT + colv] = f2bf(acc[c][r]);
    }
  }
}

// Layer-3 aggregation (bf16 in) + bias + log_softmax, col staged in LDS.
// Block = 16 nodes; 16-lane group per node; lanes 0..9 hold 4 classes each.
__global__ __launch_bounds__(256) void agg_lsm_bf16(const unsigned short* __restrict__ t,
                                                    const int* __restrict__ row_ptr,
                                                    const int* __restrict__ col,
                                                    const float* __restrict__ bias,
                                                    float* __restrict__ out, int N) {
  constexpr int CAPL = 1024;  // staged edges (mean 256)
  __shared__ int scol[CAPL];
  __shared__ int srp[17];
  int tid = threadIdx.x;
  int node0 = blockIdx.x * 16;
  int nloc = N - node0;
  if (nloc > 16) nloc = 16;
  if (tid <= nloc) srp[tid] = row_ptr[node0 + tid];
  __syncthreads();
  int gs = srp[0];
  int me = srp[nloc] - gs;
  for (int i = tid; i < me && i < CAPL; i += 256) scol[i] = col[gs + i];
  __syncthreads();

  int nl = tid >> 4;
  int c = tid & 15;  // 0..9 active
  bool act = (c < 10) && (nl < nloc);
  int ceff = (c < 10) ? c : 0;
  const unsigned short* tc = t + 4 * ceff;
  float v0 = 0.f, v1 = 0.f, v2 = 0.f, v3 = 0.f;
  if (act) {
    int beg = srp[nl] - gs;
    int end = srp[nl + 1] - gs;
    int e = beg;
    for (; e + 3 < end; e += 4) {
      int s0 = (e < CAPL) ? scol[e] : col[gs + e];
      int s1 = (e + 1 < CAPL) ? scol[e + 1] : col[gs + e + 1];
      int s2 = (e + 2 < CAPL) ? scol[e + 2] : col[gs + e + 2];
      int s3 = (e + 3 < CAPL) ? scol[e + 3] : col[gs + e + 3];
      uint2 u = *(const uint2*)(tc + (size_t)s0 * 40);
      uint2 w = *(const uint2*)(tc + (size_t)s1 * 40);
      uint2 y = *(const uint2*)(tc + (size_t)s2 * 40);
      uint2 z = *(const uint2*)(tc + (size_t)s3 * 40);
      v0 += bflo(u.x); v1 += bfhi(u.x); v2 += bflo(u.y); v3 += bfhi(u.y);
      v0 += bflo(w.x); v1 += bfhi(w.x); v2 += bflo(w.y); v3 += bfhi(w.y);
      v0 += bflo(y.x); v1 += bfhi(y.x); v2 += bflo(y.y); v3 += bfhi(y.y);
      v0 += bflo(z.x); v1 += bfhi(z.x); v2 += bflo(z.y); v3 += bfhi(z.y);
    }
    for (; e < end; ++e) {
      int s0 = (e < CAPL) ? scol[e] : col[gs + e];
      uint2 u = *(const uint2*)(tc + (size_t)s0 * 40);
      v0 += bflo(u.x); v1 += bfhi(u.x); v2 += bflo(u.y); v3 += bfhi(u.y);
    }
  }
  const float* bb = bias + 4 * ceff;
  v0 += bb[0]; v1 += bb[1]; v2 += bb[2]; v3 += bb[3];
  float m = act ? fmaxf(fmaxf(v0, v1), fmaxf(v2, v3)) : -__builtin_inff();
#pragma unroll
  for (int off = 8; off; off >>= 1) m = fmaxf(m, __shfl_xor(m, off, 64));
  float ex = act ? (__expf(v0 - m) + __expf(v1 - m) + __expf(v2 - m) + __expf(v3 - m)) : 0.f;
#pragma unroll
  for (int off = 8; off; off >>= 1) ex += __shfl_xor(ex, off, 64);
  if (act) {
    int node = node0 + nl;
    float l = m + __logf(ex);
    float* o = out + (size_t)node * 40 + 4 * c;
    o[0] = v0 - l; o[1] = v1 - l; o[2] = v2 - l; o[3] = v3 - l;
  }
}

// ================= Launch =================

extern "C" void kernel_launch(void* const* d_in, const int* in_sizes, int n_in,
                              void* d_out, int out_size, void* d_ws, size_t ws_size,
                              hipStream_t stream) {
  const float* x  = (const float*)d_in[0];
  const float* W1 = (const float*)d_in[1];
  const float* b1 = (const float*)d_in[2];
  const float* W2 = (const float*)d_in[3];
  const float* b2 = (const float*)d_in[4];
  const float* W3 = (const float*)d_in[5];
  const float* b3 = (const float*)d_in[6];
  const int* edge = (const int*)d_in[7];

  int N = in_sizes[0] / 128;  // 50000
  int E = in_sizes[7] / 2;    // 800000
  const int* srcp = edge;
  const int* dstp = edge + E;

  char* p = (char*)d_ws;
  auto alloc = [&](size_t bytes) {
    char* r = p;
    p += (bytes + 255) & ~size_t(255);
    return r;
  };
  int NB = (N + 255) >> 8;  // 196 buckets of 256 nodes
  int* partial = (int*)alloc((size_t)CB * 256 * 4);
  int* gstart  = (int*)alloc((size_t)(NB + 1) * 4);
  int* gcur    = (int*)alloc((size_t)NB * 4);
  int* row_ptr = (int*)alloc((size_t)(N + 1) * 4);
  int* packed  = (int*)alloc((size_t)E * 4);
  int* col     = (int*)alloc((size_t)E * 4);
  unsigned short* Wp1 = (unsigned short*)alloc(1536 * 8 * 2);
  unsigned short* Wp2 = (unsigned short*)alloc(1152 * 8 * 2);
  unsigned short* Wp3 = (unsigned short*)alloc(576 * 8 * 2);
  unsigned short* Tb  = (unsigned short*)alloc((size_t)N * 96 * 2);   // t1
  unsigned short* T2b = (unsigned short*)alloc((size_t)N * 96 * 2);   // t2
  unsigned short* T3b = (unsigned short*)alloc((size_t)N * 40 * 2);   // t3

  int E4 = E >> 2;
  int nbin = (E4 + ((E & 3) ? 1 : 0) + 255) / 256;
  int GB = ((N + 15) / 16 + 3) / 4;  // gemm1 blocks (4 row-tiles each)
  int FB = (N + 63) / 64;            // fused blocks (64 nodes each)

  // 1: bucket count + W1/W2/W3 pack
  count_pack<<<CB + 13, 256, 0, stream>>>(dstp, partial, E, W1, W2, W3, Wp1, Wp2, Wp3);
  // 2: scan bucket totals
  scan_kernel<<<1, 256, 0, stream>>>(partial, gstart, gcur, row_ptr, NB, N, E);
  // 3: bin edges + gemm1 (independent halves, overlap)
  bin_gemm1<<<nbin + GB, 256, 0, stream>>>(srcp, dstp, gcur, packed, E, NB, nbin,
                                           x, Wp1, Tb, N);
  // 4: per-bucket CSR finalize
  build_local_csr<<<NB, 256, 0, stream>>>(packed, gstart, row_ptr, col, N);
  // 5: t2 = relu(agg(t1)+b1) @ W2
  fused_agg_gemm<6, 96, 96><<<FB, 256, 0, stream>>>(Tb, row_ptr, col, b1, Wp2, T2b, N);
  // 6: t3 = relu(agg(t2)+b2) @ W3
  fused_agg_gemm<3, 40, 40><<<FB, 256, 0, stream>>>(T2b, row_ptr, col, b2, Wp3, T3b, N);
  // 7: out = log_softmax(agg(t3) + b3)
  agg_lsm_bf16<<<(N + 15) / 16, 256, 0, stream>>>(T3b, row_ptr, col, b3, (float*)d_out, N);
}

// Round 9
// 196.610 us; speedup vs baseline: 1.1345x; 1.0333x over previous
//
#include <hip/hip_runtime.h>
#include <math.h>

typedef __attribute__((ext_vector_type(8))) short bf16x8;
typedef __attribute__((ext_vector_type(4))) float f32x4;

__device__ __forceinline__ unsigned short f2bf(float f) {
  unsigned u = __float_as_uint(f);
  u += 0x7fffu + ((u >> 16) & 1u);  // round-to-nearest-even
  return (unsigned short)(u >> 16);
}
__device__ __forceinline__ float bflo(unsigned u) { return __uint_as_float(u << 16); }
__device__ __forceinline__ float bfhi(unsigned u) { return __uint_as_float(u & 0xffff0000u); }

// ================= CSR via two-level bucket binning =================
// Buckets of 128 nodes (NB = ceil(N/128) = 391 <= 512). packed edge =
// (d_local<<16)|src. Requires N <= 65536 — N = 50000 here.

constexpr int CB = 64;    // histogram blocks
constexpr int EB = 4096;  // edges per binning block

// Dispatch 1: [0,CB) histogram partials (512-wide); [CB,CB+13) pack W1/W2/W3
// to MFMA B-fragment order: fragment (s,ct): lane l holds
// B[k=s*32+(l>>4)*8+j][col=ct*16+(l&15)], j=0..7, 8 contiguous bf16.
__global__ __launch_bounds__(256) void count_pack(const int* __restrict__ dst,
                                                  int* __restrict__ partial, int E,
                                                  const float* __restrict__ W1,
                                                  const float* __restrict__ W2,
                                                  const float* __restrict__ W3,
                                                  unsigned short* __restrict__ Wp1,
                                                  unsigned short* __restrict__ Wp2,
                                                  unsigned short* __restrict__ Wp3) {
  int tid = threadIdx.x;
  if (blockIdx.x < CB) {
    __shared__ int bkt[512];
    bkt[tid] = 0;
    bkt[tid + 256] = 0;
    __syncthreads();
    int E4 = E >> 2;
    const int4* d4 = (const int4*)dst;
    for (int i = blockIdx.x * 256 + tid; i < E4; i += CB * 256) {
      int4 d = d4[i];
      atomicAdd(&bkt[d.x >> 7], 1);
      atomicAdd(&bkt[d.y >> 7], 1);
      atomicAdd(&bkt[d.z >> 7], 1);
      atomicAdd(&bkt[d.w >> 7], 1);
    }
    if (blockIdx.x == 0 && tid < (E & 3)) atomicAdd(&bkt[dst[E4 * 4 + tid] >> 7], 1);
    __syncthreads();
    partial[blockIdx.x * 512 + tid] = bkt[tid];
    partial[blockIdx.x * 512 + tid + 256] = bkt[tid + 256];
    return;
  }
  int gid = (blockIdx.x - CB) * 256 + tid;
  const float* W;
  unsigned short* Wp;
  int t, NCTT, M, MV;
  if (gid < 1536) {            // W1: 4 ksteps * 6 coltiles * 64 lanes
    W = W1; Wp = Wp1; t = gid; NCTT = 6; M = 96; MV = 96;
  } else if (gid < 2688) {     // W2: 3 * 6 * 64
    W = W2; Wp = Wp2; t = gid - 1536; NCTT = 6; M = 96; MV = 96;
  } else if (gid < 3264) {     // W3: 3 * 3 * 64 (cols >= 40 zero-padded)
    W = W3; Wp = Wp3; t = gid - 2688; NCTT = 3; M = 40; MV = 40;
  } else {
    return;
  }
  int lane = t & 63;
  int frag = t >> 6;
  int s = frag / NCTT;
  int ct = frag - s * NCTT;
  int colv = ct * 16 + (lane & 15);
  int k0 = s * 32 + (lane >> 4) * 8;
  union { unsigned short s[8]; uint4 u; } pk;
#pragma unroll
  for (int j = 0; j < 8; ++j) {
    float v = (colv < MV) ? W[(k0 + j) * M + colv] : 0.f;
    pk.s[j] = f2bf(v);
  }
  ((uint4*)Wp)[t] = pk.u;
}

// One block: reduce partials + exclusive scan over 512 bucket slots.
__global__ __launch_bounds__(256) void scan_kernel(const int* __restrict__ partial,
                                                   int* __restrict__ gstart,
                                                   int* __restrict__ gcur,
                                                   int* __restrict__ row_ptr,
                                                   int NB, int N, int E) {
  __shared__ int sm[512];
  int tid = threadIdx.x;
  int s0 = 0, s1 = 0;
#pragma unroll 8
  for (int i = 0; i < CB; ++i) {
    s0 += partial[i * 512 + tid];
    s1 += partial[i * 512 + tid + 256];
  }
  sm[tid] = s0;
  sm[tid + 256] = s1;
  __syncthreads();
  for (int off = 1; off < 512; off <<= 1) {
    int a0 = (tid >= off) ? sm[tid - off] : 0;
    int i1 = tid + 256;
    int a1 = (i1 >= off) ? sm[i1 - off] : 0;
    __syncthreads();
    sm[tid] += a0;
    sm[i1] += a1;
    __syncthreads();
  }
  int e0 = sm[tid] - s0;
  int e1 = sm[tid + 256] - s1;
  if (tid < NB) { gstart[tid] = e0; gcur[tid] = e0; }
  int b1 = tid + 256;
  if (b1 < NB) { gstart[b1] = e1; gcur[b1] = e1; }
  if (tid == 255) gstart[NB] = sm[511];  // buckets >= NB are empty
  if (tid == 0) row_ptr[N] = E;
}

// Dispatch 3: [0,NBIN) LDS-staged binning (4096 edges/block, dense sorted-run
// writes); [NBIN,..) gemm1 Tb = bf16(x) @ W1 with packed Wp1. Independent.
__global__ __launch_bounds__(256) void bin_gemm1(const int* __restrict__ src,
                                                 const int* __restrict__ dst,
                                                 int* __restrict__ gcur,
                                                 int* __restrict__ packed, int E, int NB,
                                                 int NBIN, const float* __restrict__ x,
                                                 const unsigned short* __restrict__ Wp1,
                                                 unsigned short* __restrict__ Tb, int N) {
  __shared__ int lcnt[512];
  __shared__ int lstart[512];
  __shared__ int gbase[512];
  __shared__ int cur[512];
  __shared__ int stage[EB];
  int tid = threadIdx.x;
  if (blockIdx.x < NBIN) {
    lcnt[tid] = 0;
    lcnt[tid + 256] = 0;
    __syncthreads();
    int E4 = E >> 2;
    int base4 = blockIdx.x * (EB >> 2);  // int4 base
    int sv[16], dv[16];
    int nv = 0;
#pragma unroll
    for (int j = 0; j < 4; ++j) {
      int idx4 = base4 + j * 256 + tid;
      if (idx4 < E4 && idx4 < base4 + (EB >> 2)) {
        int4 s4 = ((const int4*)src)[idx4];
        int4 d4 = ((const int4*)dst)[idx4];
        sv[j * 4 + 0] = s4.x; dv[j * 4 + 0] = d4.x;
        sv[j * 4 + 1] = s4.y; dv[j * 4 + 1] = d4.y;
        sv[j * 4 + 2] = s4.z; dv[j * 4 + 2] = d4.z;
        sv[j * 4 + 3] = s4.w; dv[j * 4 + 3] = d4.w;
        nv = j * 4 + 4;
      }
    }
#pragma unroll
    for (int i = 0; i < 16; ++i)
      if (i < nv) atomicAdd(&lcnt[dv[i] >> 7], 1);
    bool last = (blockIdx.x == NBIN - 1);
    int tl = E & 3;
    if (last && tid == 0)
      for (int t = 0; t < tl; ++t) atomicAdd(&lcnt[dst[E4 * 4 + t] >> 7], 1);
    __syncthreads();
    // exclusive scan of 512 counts
    lstart[tid] = lcnt[tid];
    lstart[tid + 256] = lcnt[tid + 256];
    __syncthreads();
    for (int off = 1; off < 512; off <<= 1) {
      int a0 = (tid >= off) ? lstart[tid - off] : 0;
      int i1 = tid + 256;
      int a1 = (i1 >= off) ? lstart[i1 - off] : 0;
      __syncthreads();
      lstart[tid] += a0;
      lstart[i1] += a1;
      __syncthreads();
    }
    int e0 = lstart[tid] - lcnt[tid];
    int e1 = lstart[tid + 256] - lcnt[tid + 256];
    __syncthreads();
    lstart[tid] = e0; cur[tid] = e0;
    lstart[tid + 256] = e1; cur[tid + 256] = e1;
    __syncthreads();
    // place into LDS stage (bucket-sorted)
#pragma unroll
    for (int i = 0; i < 16; ++i)
      if (i < nv) {
        int b = dv[i] >> 7;
        int p = atomicAdd(&cur[b], 1);
        stage[p] = ((dv[i] & 127) << 16) | (sv[i] & 0xffff);
      }
    if (last && tid == 0)
      for (int t = 0; t < tl; ++t) {
        int d = dst[E4 * 4 + t], s = src[E4 * 4 + t];
        int p = atomicAdd(&cur[d >> 7], 1);
        stage[p] = ((d & 127) << 16) | (s & 0xffff);
      }
    // reserve global runs
    if (lcnt[tid]) gbase[tid] = atomicAdd(&gcur[tid], lcnt[tid]);
    if (lcnt[tid + 256]) gbase[tid + 256] = atomicAdd(&gcur[tid + 256], lcnt[tid + 256]);
    __syncthreads();
    // dense run writes; bucket of position via binary search on lstart
    int meB = lstart[511] + lcnt[511];
    for (int i = tid; i < meB; i += 256) {
      int lo = 0, hi = 511;
      while (lo < hi) {
        int mid = (lo + hi + 1) >> 1;
        if (lstart[mid] <= i) lo = mid; else hi = mid - 1;
      }
      packed[gbase[lo] + (i - lstart[lo])] = stage[i];
    }
    return;
  }
  // ---- gemm1: 16 rows x 96 cols per wave, KSTEPS=4 ----
  int bx = blockIdx.x - NBIN;
  int wid = tid >> 6;
  int lane = tid & 63;
  int rt = bx * 4 + wid;
  if (rt * 16 >= N) return;
  int quad = lane >> 4;
  int lm = lane & 15;
  union BU { uint4 u; bf16x8 v; };
  f32x4 acc[6];
#pragma unroll
  for (int c = 0; c < 6; ++c) acc[c] = (f32x4){0.f, 0.f, 0.f, 0.f};
  int row = rt * 16 + lm;
  if (row >= N) row = N - 1;  // safe dup read; epilogue guards rows
  const uint4* wp4 = (const uint4*)Wp1;
#pragma unroll
  for (int s = 0; s < 4; ++s) {
    int k0 = s * 32 + quad * 8;
    const float* Af = x + (size_t)row * 128 + k0;
    float4 x0 = *(const float4*)(Af);
    float4 x1 = *(const float4*)(Af + 4);
    union { unsigned short s[8]; bf16x8 v; } au;
    au.s[0] = f2bf(x0.x); au.s[1] = f2bf(x0.y); au.s[2] = f2bf(x0.z); au.s[3] = f2bf(x0.w);
    au.s[4] = f2bf(x1.x); au.s[5] = f2bf(x1.y); au.s[6] = f2bf(x1.z); au.s[7] = f2bf(x1.w);
#pragma unroll
    for (int c = 0; c < 6; ++c) {
      BU bu;
      bu.u = wp4[(s * 6 + c) * 64 + lane];
      acc[c] = __builtin_amdgcn_mfma_f32_16x16x32_bf16(au.v, bu.v, acc[c], 0, 0, 0);
    }
  }
#pragma unroll
  for (int c = 0; c < 6; ++c) {
    int colv = c * 16 + lm;
#pragma unroll
    for (int r = 0; r < 4; ++r) {
      int orow = rt * 16 + quad * 4 + r;
      if (orow < N) Tb[(size_t)orow * 96 + colv] = f2bf(acc[c][r]);
    }
  }
}

// One block per 128-node bucket: local count -> local scan -> row_ptr + col.
__global__ __launch_bounds__(256) void build_local_csr(const int* __restrict__ packed,
                                                       const int* __restrict__ gstart,
                                                       int* __restrict__ row_ptr,
                                                       int* __restrict__ col, int N) {
  __shared__ int cnt[128];
  __shared__ int sm[128];
  int b = blockIdx.x, tid = threadIdx.x;
  int gs = gstart[b], ge = gstart[b + 1];
  int me = ge - gs;
  int node0 = b << 7;
  int RL = N - node0;
  if (RL > 128) RL = 128;
  if (tid < 128) cnt[tid] = 0;
  __syncthreads();
  for (int i = tid; i < me; i += 256) atomicAdd(&cnt[packed[gs + i] >> 16], 1);
  __syncthreads();
  if (tid < 128) sm[tid] = cnt[tid];
  __syncthreads();
  for (int off = 1; off < 128; off <<= 1) {
    int u = (tid >= off && tid < 128) ? sm[tid - off] : 0;
    __syncthreads();
    if (tid < 128) sm[tid] += u;
    __syncthreads();
  }
  if (tid < 128) {
    int excl = gs + sm[tid] - cnt[tid];
    cnt[tid] = excl;  // repurpose as cursor
    if (tid < RL) row_ptr[node0 + tid] = excl;
  }
  __syncthreads();
  for (int i = tid; i < me; i += 256) {
    int pk = packed[gs + i];
    int p = atomicAdd(&cnt[pk >> 16], 1);
    col[p] = pk & 0xffff;
  }
}

// ================= Fused aggregation + GEMM =================
// Block owns 64 nodes; col + row_ptr staged in LDS. Phase A: h=relu(agg+bias)
// -> LDS (stride 104), gather unrolled x4. Phase B: 4 waves x 16-row MFMA
// tiles; B-frags reloaded per k-step (VGPR <= 73 for 7 blocks/CU).

template <int NCT, int MOUT, int MVALID>
__global__ __launch_bounds__(256, 7) void fused_agg_gemm(
    const unsigned short* __restrict__ tin, const int* __restrict__ row_ptr,
    const int* __restrict__ col, const float* __restrict__ bias,
    const unsigned short* __restrict__ Wp, unsigned short* __restrict__ outp, int N) {
  constexpr int LST = 104;   // bf16 units per LDS row
  constexpr int CAP = 1536;  // staged edges (mean 1024, ~16 sigma) + global fallback
  __shared__ unsigned short sH[64 * LST];
  __shared__ int scol[CAP];
  __shared__ int srp[65];
  int tid = threadIdx.x;
  int node0 = blockIdx.x * 64;
  int nloc = N - node0;
  if (nloc > 64) nloc = 64;
  if (tid <= nloc) srp[tid] = row_ptr[node0 + tid];
  __syncthreads();
  int gs = srp[0];
  int me = srp[nloc] - gs;
  for (int i = tid; i < me && i < CAP; i += 256) scol[i] = col[gs + i];
  __syncthreads();

  // ---- Phase A: aggregate 64 nodes x 12 chunks of 8 bf16, unroll x4 ----
#pragma unroll
  for (int it = 0; it < 3; ++it) {
    int u = tid + it * 256;
    int nl = u / 12;
    int c = u - nl * 12;
    if (nl < nloc) {
      int beg = srp[nl] - gs;
      int end = srp[nl + 1] - gs;
      const unsigned short* tc = tin + 8 * c;
      float a0 = 0.f, a1 = 0.f, a2 = 0.f, a3 = 0.f, a4 = 0.f, a5 = 0.f, a6 = 0.f, a7 = 0.f;
      int e = beg;
      for (; e + 3 < end; e += 4) {
        int s0 = (e < CAP) ? scol[e] : col[gs + e];
        int s1 = (e + 1 < CAP) ? scol[e + 1] : col[gs + e + 1];
        int s2 = (e + 2 < CAP) ? scol[e + 2] : col[gs + e + 2];
        int s3 = (e + 3 < CAP) ? scol[e + 3] : col[gs + e + 3];
        uint4 u0 = *(const uint4*)(tc + (size_t)s0 * 96);
        uint4 u1 = *(const uint4*)(tc + (size_t)s1 * 96);
        uint4 u2 = *(const uint4*)(tc + (size_t)s2 * 96);
        uint4 u3 = *(const uint4*)(tc + (size_t)s3 * 96);
        a0 += bflo(u0.x); a1 += bfhi(u0.x); a2 += bflo(u0.y); a3 += bfhi(u0.y);
        a4 += bflo(u0.z); a5 += bfhi(u0.z); a6 += bflo(u0.w); a7 += bfhi(u0.w);
        a0 += bflo(u1.x); a1 += bfhi(u1.x); a2 += bflo(u1.y); a3 += bfhi(u1.y);
        a4 += bflo(u1.z); a5 += bfhi(u1.z); a6 += bflo(u1.w); a7 += bfhi(u1.w);
        a0 += bflo(u2.x); a1 += bfhi(u2.x); a2 += bflo(u2.y); a3 += bfhi(u2.y);
        a4 += bflo(u2.z); a5 += bfhi(u2.z); a6 += bflo(u2.w); a7 += bfhi(u2.w);
        a0 += bflo(u3.x); a1 += bfhi(u3.x); a2 += bflo(u3.y); a3 += bfhi(u3.y);
        a4 += bflo(u3.z); a5 += bfhi(u3.z); a6 += bflo(u3.w); a7 += bfhi(u3.w);
      }
      for (; e < end; ++e) {
        int s0 = (e < CAP) ? scol[e] : col[gs + e];
        uint4 u4 = *(const uint4*)(tc + (size_t)s0 * 96);
        a0 += bflo(u4.x); a1 += bfhi(u4.x); a2 += bflo(u4.y); a3 += bfhi(u4.y);
        a4 += bflo(u4.z); a5 += bfhi(u4.z); a6 += bflo(u4.w); a7 += bfhi(u4.w);
      }
      const float* b = bias + 8 * c;
      union { unsigned short s[8]; uint4 u; } pk;
      pk.s[0] = f2bf(fmaxf(a0 + b[0], 0.f));
      pk.s[1] = f2bf(fmaxf(a1 + b[1], 0.f));
      pk.s[2] = f2bf(fmaxf(a2 + b[2], 0.f));
      pk.s[3] = f2bf(fmaxf(a3 + b[3], 0.f));
      pk.s[4] = f2bf(fmaxf(a4 + b[4], 0.f));
      pk.s[5] = f2bf(fmaxf(a5 + b[5], 0.f));
      pk.s[6] = f2bf(fmaxf(a6 + b[6], 0.f));
      pk.s[7] = f2bf(fmaxf(a7 + b[7], 0.f));
      *(uint4*)&sH[nl * LST + c * 8] = pk.u;
    }
  }
  __syncthreads();

  // ---- Phase B: MFMA tile per wave; per-step B-frag reload ----
  int wid = tid >> 6;
  int lane = tid & 63;
  int rt16 = wid * 16;
  if (node0 + rt16 >= N) return;
  int quad = lane >> 4;
  int lm = lane & 15;
  union BU { uint4 u; bf16x8 v; };
  f32x4 acc[NCT];
#pragma unroll
  for (int c = 0; c < NCT; ++c) acc[c] = (f32x4){0.f, 0.f, 0.f, 0.f};
  const uint4* wp4 = (const uint4*)Wp;
#pragma unroll
  for (int s = 0; s < 3; ++s) {
    BU au;
    au.u = *(const uint4*)&sH[(rt16 + lm) * LST + s * 32 + quad * 8];
#pragma unroll
    for (int c = 0; c < NCT; ++c) {
      BU bu;
      bu.u = wp4[(s * NCT + c) * 64 + lane];
      acc[c] = __builtin_amdgcn_mfma_f32_16x16x32_bf16(au.v, bu.v, acc[c], 0, 0, 0);
    }
  }
#pragma unroll
  for (int c = 0; c < NCT; ++c) {
    int colv = c * 16 + lm;
    if (colv >= MVALID) continue;
#pragma unroll
    for (int r = 0; r < 4; ++r) {
      int orow = node0 + rt16 + quad * 4 + r;
      if (orow < N) outp[(size_t)orow * MOUT + colv] = f2bf(acc[c][r]);
    }
  }
}

// Layer-3 aggregation (bf16 in) + bias + log_softmax, col staged in LDS.
// Block = 16 nodes; 16-lane group per node; lanes 0..9 hold 4 classes each.
__global__ __launch_bounds__(256) void agg_lsm_bf16(const unsigned short* __restrict__ t,
                                                    const int* __restrict__ row_ptr,
                                                    const int* __restrict__ col,
                                                    const float* __restrict__ bias,
                                                    float* __restrict__ out, int N) {
  constexpr int CAPL = 1024;  // staged edges (mean 256)
  __shared__ int scol[CAPL];
  __shared__ int srp[17];
  int tid = threadIdx.x;
  int node0 = blockIdx.x * 16;
  int nloc = N - node0;
  if (nloc > 16) nloc = 16;
  if (tid <= nloc) srp[tid] = row_ptr[node0 + tid];
  __syncthreads();
  int gs = srp[0];
  int me = srp[nloc] - gs;
  for (int i = tid; i < me && i < CAPL; i += 256) scol[i] = col[gs + i];
  __syncthreads();

  int nl = tid >> 4;
  int c = tid & 15;  // 0..9 active
  bool act = (c < 10) && (nl < nloc);
  int ceff = (c < 10) ? c : 0;
  const unsigned short* tc = t + 4 * ceff;
  float v0 = 0.f, v1 = 0.f, v2 = 0.f, v3 = 0.f;
  if (act) {
    int beg = srp[nl] - gs;
    int end = srp[nl + 1] - gs;
    int e = beg;
    for (; e + 3 < end; e += 4) {
      int s0 = (e < CAPL) ? scol[e] : col[gs + e];
      int s1 = (e + 1 < CAPL) ? scol[e + 1] : col[gs + e + 1];
      int s2 = (e + 2 < CAPL) ? scol[e + 2] : col[gs + e + 2];
      int s3 = (e + 3 < CAPL) ? scol[e + 3] : col[gs + e + 3];
      uint2 u = *(const uint2*)(tc + (size_t)s0 * 40);
      uint2 w = *(const uint2*)(tc + (size_t)s1 * 40);
      uint2 y = *(const uint2*)(tc + (size_t)s2 * 40);
      uint2 z = *(const uint2*)(tc + (size_t)s3 * 40);
      v0 += bflo(u.x); v1 += bfhi(u.x); v2 += bflo(u.y); v3 += bfhi(u.y);
      v0 += bflo(w.x); v1 += bfhi(w.x); v2 += bflo(w.y); v3 += bfhi(w.y);
      v0 += bflo(y.x); v1 += bfhi(y.x); v2 += bflo(y.y); v3 += bfhi(y.y);
      v0 += bflo(z.x); v1 += bfhi(z.x); v2 += bflo(z.y); v3 += bfhi(z.y);
    }
    for (; e < end; ++e) {
      int s0 = (e < CAPL) ? scol[e] : col[gs + e];
      uint2 u = *(const uint2*)(tc + (size_t)s0 * 40);
      v0 += bflo(u.x); v1 += bfhi(u.x); v2 += bflo(u.y); v3 += bfhi(u.y);
    }
  }
  const float* bb = bias + 4 * ceff;
  v0 += bb[0]; v1 += bb[1]; v2 += bb[2]; v3 += bb[3];
  float m = act ? fmaxf(fmaxf(v0, v1), fmaxf(v2, v3)) : -__builtin_inff();
#pragma unroll
  for (int off = 8; off; off >>= 1) m = fmaxf(m, __shfl_xor(m, off, 64));
  float ex = act ? (__expf(v0 - m) + __expf(v1 - m) + __expf(v2 - m) + __expf(v3 - m)) : 0.f;
#pragma unroll
  for (int off = 8; off; off >>= 1) ex += __shfl_xor(ex, off, 64);
  if (act) {
    int node = node0 + nl;
    float l = m + __logf(ex);
    float* o = out + (size_t)node * 40 + 4 * c;
    o[0] = v0 - l; o[1] = v1 - l; o[2] = v2 - l; o[3] = v3 - l;
  }
}

// ================= Launch =================

extern "C" void kernel_launch(void* const* d_in, const int* in_sizes, int n_in,
                              void* d_out, int out_size, void* d_ws, size_t ws_size,
                              hipStream_t stream) {
  const float* x  = (const float*)d_in[0];
  const float* W1 = (const float*)d_in[1];
  const float* b1 = (const float*)d_in[2];
  const float* W2 = (const float*)d_in[3];
  const float* b2 = (const float*)d_in[4];
  const float* W3 = (const float*)d_in[5];
  const float* b3 = (const float*)d_in[6];
  const int* edge = (const int*)d_in[7];

  int N = in_sizes[0] / 128;  // 50000
  int E = in_sizes[7] / 2;    // 800000
  const int* srcp = edge;
  const int* dstp = edge + E;

  char* p = (char*)d_ws;
  auto alloc = [&](size_t bytes) {
    char* r = p;
    p += (bytes + 255) & ~size_t(255);
    return r;
  };
  int NB = (N + 127) >> 7;  // 391 buckets of 128 nodes
  int* partial = (int*)alloc((size_t)CB * 512 * 4);
  int* gstart  = (int*)alloc((size_t)(NB + 1) * 4);
  int* gcur    = (int*)alloc((size_t)NB * 4);
  int* row_ptr = (int*)alloc((size_t)(N + 1) * 4);
  int* packed  = (int*)alloc((size_t)E * 4);
  int* col     = (int*)alloc((size_t)E * 4);
  unsigned short* Wp1 = (unsigned short*)alloc(1536 * 8 * 2);
  unsigned short* Wp2 = (unsigned short*)alloc(1152 * 8 * 2);
  unsigned short* Wp3 = (unsigned short*)alloc(576 * 8 * 2);
  unsigned short* Tb  = (unsigned short*)alloc((size_t)N * 96 * 2);   // t1
  unsigned short* T2b = (unsigned short*)alloc((size_t)N * 96 * 2);   // t2
  unsigned short* T3b = (unsigned short*)alloc((size_t)N * 40 * 2);   // t3

  int NBIN = (E + EB - 1) / EB;      // 196 binning blocks
  int GB = ((N + 15) / 16 + 3) / 4;  // gemm1 blocks (4 row-tiles each)
  int FB = (N + 63) / 64;            // fused blocks (64 nodes each)

  // 1: bucket count + W1/W2/W3 pack
  count_pack<<<CB + 13, 256, 0, stream>>>(dstp, partial, E, W1, W2, W3, Wp1, Wp2, Wp3);
  // 2: scan bucket totals
  scan_kernel<<<1, 256, 0, stream>>>(partial, gstart, gcur, row_ptr, NB, N, E);
  // 3: LDS-staged bin + gemm1 (independent halves, overlap)
  bin_gemm1<<<NBIN + GB, 256, 0, stream>>>(srcp, dstp, gcur, packed, E, NB, NBIN,
                                           x, Wp1, Tb, N);
  // 4: per-bucket CSR finalize
  build_local_csr<<<NB, 256, 0, stream>>>(packed, gstart, row_ptr, col, N);
  // 5: t2 = relu(agg(t1)+b1) @ W2
  fused_agg_gemm<6, 96, 96><<<FB, 256, 0, stream>>>(Tb, row_ptr, col, b1, Wp2, T2b, N);
  // 6: t3 = relu(agg(t2)+b2) @ W3
  fused_agg_gemm<3, 40, 40><<<FB, 256, 0, stream>>>(T2b, row_ptr, col, b2, Wp3, T3b, N);
  // 7: out = log_softmax(agg(t3) + b3)
  agg_lsm_bf16<<<(N + 15) / 16, 256, 0, stream>>>(T3b, row_ptr, col, b3, (float*)d_out, N);
}